// Round 2
// baseline (3412.214 us; speedup 1.0000x reference)
//
#include <hip/hip_runtime.h>
#include <cmath>

// Problem constants (from reference setup_inputs)
#define Bc 8
#define Nc 4096
#define Sc 1024
#define Kc 32
#define Mc (Bc*Sc*Kc)   // 262144 rows

__device__ __forceinline__ float gelu_f(float x){
  return 0.5f*x*(1.0f + erff(x*0.70710678f));
}

// ---------------- tp MLP: tp[l][b][c] = gelu(t_embed[b]) @ wt_l.T + bt_l ----------------
__global__ __launch_bounds__(256) void tp_kernel(const float* __restrict__ t_embed,
    const float* __restrict__ wt0, const float* __restrict__ bt0,
    const float* __restrict__ wt1, const float* __restrict__ bt1,
    const float* __restrict__ wt2, const float* __restrict__ bt2,
    float* __restrict__ tp){
  __shared__ float ge[Bc*128];
  const int tid = threadIdx.x;
  for (int i = tid; i < Bc*128; i += 256){
    ge[i] = gelu_f(t_embed[i]);
  }
  __syncthreads();
  // layout: tp[(l*8 + b)*68 + c], pad c>=ci with 0
  for (int i = tid; i < 3*Bc*68; i += 256){
    int l = i / (Bc*68);
    int r = i - l*(Bc*68);
    int b = r / 68;
    int c = r - b*68;
    int ci = (l==0) ? 67 : 64;
    float v = 0.0f;
    if (c < ci){
      const float* wt = (l==0)?wt0:((l==1)?wt1:wt2);
      const float* bt = (l==0)?bt0:((l==1)?bt1:bt2);
      const float* w = wt + c*128;
      const float* g = ge + b*128;
      float acc = 0.0f;
      for (int t=0;t<128;++t) acc = fmaf(g[t], w[t], acc);
      v = acc + bt[c];
    }
    tp[i] = v;
  }
}

// ---------------- FPS: one block per batch, bitwise-exact vs numpy ----------------
__global__ __launch_bounds__(512) void fps_kernel(const float* __restrict__ xyz,
                                                  float* __restrict__ new_xyz){
  const int b = blockIdx.x;
  const int tid = threadIdx.x;
  const float* xb = xyz + b*Nc*3;
  float px[8], py[8], pz[8], dist[8];
#pragma unroll
  for (int j=0;j<8;++j){
    int i = tid + (j<<9);
    px[j]=xb[i*3+0]; py[j]=xb[i*3+1]; pz[j]=xb[i*3+2];
    dist[j]=1e10f;
  }
  __shared__ float s_cx, s_cy, s_cz;
  __shared__ float swv[8], swx[8], swy[8], swz[8];
  __shared__ int swi[8];
  if (tid==0){ s_cx=px[0]; s_cy=py[0]; s_cz=pz[0]; }  // index 0 is tid0's j=0
  __syncthreads();
  for (int it=0; it<Sc; ++it){
    const float cx=s_cx, cy=s_cy, cz=s_cz;
    if (tid==0){
      float* o = new_xyz + ((size_t)b*Sc + it)*3;
      o[0]=cx; o[1]=cy; o[2]=cz;
    }
    float bv = -1.0f; int bi = 0;
#pragma unroll
    for (int j=0;j<8;++j){
      // exact numpy order: ((dx*dx + dy*dy) + dz*dz), no FMA contraction
      float dx=__fsub_rn(px[j],cx);
      float dy=__fsub_rn(py[j],cy);
      float dz=__fsub_rn(pz[j],cz);
      float dd=__fadd_rn(__fadd_rn(__fmul_rn(dx,dx),__fmul_rn(dy,dy)),__fmul_rn(dz,dz));
      float dn=fminf(dist[j],dd);
      dist[j]=dn;
      if (dn > bv){ bv=dn; bi=tid+(j<<9); }   // strict >  => lowest index on tie (j ascending)
    }
    // fetch best coords with static indexing
    const int bj = bi >> 9;
    float bx=px[0], by=py[0], bz=pz[0];
#pragma unroll
    for (int j=1;j<8;++j){
      if (bj==j){ bx=px[j]; by=py[j]; bz=pz[j]; }
    }
    // wave reduce: max value, tie -> min index
#pragma unroll
    for (int off=32; off; off>>=1){
      float ov=__shfl_down(bv,off);
      int   oi=__shfl_down(bi,off);
      float ox=__shfl_down(bx,off);
      float oy=__shfl_down(by,off);
      float oz=__shfl_down(bz,off);
      if (ov>bv || (ov==bv && oi<bi)){ bv=ov; bi=oi; bx=ox; by=oy; bz=oz; }
    }
    const int lane = tid & 63, wv = tid >> 6;
    __syncthreads();
    if (lane==0){ swv[wv]=bv; swi[wv]=bi; swx[wv]=bx; swy[wv]=by; swz[wv]=bz; }
    __syncthreads();
    if (tid==0){
      float fv=swv[0]; int fi=swi[0]; float fx=swx[0], fy=swy[0], fz=swz[0];
#pragma unroll
      for (int k2=1;k2<8;++k2){
        float ov=swv[k2]; int oi=swi[k2];
        if (ov>fv || (ov==fv && oi<fi)){ fv=ov; fi=oi; fx=swx[k2]; fy=swy[k2]; fz=swz[k2]; }
      }
      s_cx=fx; s_cy=fy; s_cz=fz;
    }
    __syncthreads();
  }
}

// ---------------- points (B,C,N) -> pointsT (B,N,C) ----------------
__global__ __launch_bounds__(256) void transpose_kernel(const float* __restrict__ points,
                                                        float* __restrict__ pointsT){
  const int b = blockIdx.y;
  const int n0 = blockIdx.x << 6;
  __shared__ float tile[64][65];
  const int tid = threadIdx.x;
  const int sub = tid >> 6;      // 0..3
  const int ln  = tid & 63;
#pragma unroll 4
  for (int cp=0; cp<16; ++cp){
    int c = (cp<<2) + sub;
    tile[c][ln] = points[((size_t)(b*64+c))*Nc + n0 + ln];
  }
  __syncthreads();
#pragma unroll 4
  for (int np=0; np<16; ++np){
    int nl = (np<<2) + sub;
    pointsT[((size_t)(b*Nc + n0 + nl))*64 + ln] = tile[ln][nl];
  }
}

// ---------------- ball query: 1 wave per centroid ----------------
__global__ __launch_bounds__(256) void ball_kernel(const float* __restrict__ xyz,
    const float* __restrict__ new_xyz, int* __restrict__ ballidx){
  const int g = (blockIdx.x<<2) + (threadIdx.x>>6);   // centroid id in [0, B*S)
  const int lane = threadIdx.x & 63;
  const int w = threadIdx.x >> 6;
  const int b = g >> 10;
  const float* xb = xyz + b*Nc*3;
  const float cx = new_xyz[g*3+0];
  const float cy = new_xyz[g*3+1];
  const float cz = new_xyz[g*3+2];
  __shared__ int sidx[4][32];
  int total = 0;
  for (int base=0; base<Nc; base+=64){
    const int i = base + lane;
    float dx=__fsub_rn(cx, xb[i*3+0]);
    float dy=__fsub_rn(cy, xb[i*3+1]);
    float dz=__fsub_rn(cz, xb[i*3+2]);
    float sq=__fadd_rn(__fadd_rn(__fmul_rn(dx,dx),__fmul_rn(dy,dy)),__fmul_rn(dz,dz));
    bool hit = !(sq > 0.04f);                     // sqr <= R^2, matching reference exactly
    unsigned long long m = __ballot(hit);
    if (hit){
      int pos = total + (int)__popcll(m & ((1ull<<lane)-1ull));
      if (pos < 32) sidx[w][pos] = i;
    }
    total += (int)__popcll(m);
    if (total >= 32) break;
  }
  __syncthreads();  // waves diverge in loop trip count; also orders LDS writes before reads
  const int fill = (total < 32) ? total : 32;     // >=1 always (centroid itself is a hit)
  const int first = sidx[w][0];
  if (lane >= fill && lane < 32) sidx[w][lane] = first;
  if (lane < 32) ballidx[(g<<5)+lane] = sidx[w][lane];
}

// ---------------- gather + concat: X (M x 68), cols 0..2 rel xyz, 3..66 points, 67 pad=0 ----------------
__global__ __launch_bounds__(256) void gather_kernel(const float* __restrict__ xyz,
    const float* __restrict__ new_xyz, const float* __restrict__ pointsT,
    const int* __restrict__ ballidx, float* __restrict__ X){
  const int bs = blockIdx.x;
  const int b = bs >> 10;
  const int w = threadIdx.x >> 6;
  const int lane = threadIdx.x & 63;
  const float cx=new_xyz[bs*3+0], cy=new_xyz[bs*3+1], cz=new_xyz[bs*3+2];
  for (int k=w; k<32; k+=4){
    const int pidx = ballidx[(bs<<5)+k];
    const float* pt = pointsT + ((size_t)((b<<12)+pidx))*64;
    const float* xp = xyz + ((size_t)((b<<12)+pidx))*3;
    float* xr = X + (size_t)((bs<<5)+k)*68;
    float v;
    if      (lane==0) v = __fsub_rn(xp[0], cx);
    else if (lane==1) v = __fsub_rn(xp[1], cy);
    else if (lane==2) v = __fsub_rn(xp[2], cz);
    else              v = pt[lane-3];
    xr[lane] = v;
    if (lane < 4){
      int c = 64 + lane;
      xr[c] = (c<67) ? pt[c-3] : 0.0f;
    }
  }
}

// ---------------- 1x1 conv matmul + fused per-block BN partial sums ----------------
// y[m][o] = sum_c (x[m][c] + tp[b][c]) * wc[o_base+o][c]   (bc omitted: cancels in BN exactly)
template<int CI_REAL, int CI_PAD, int LDX>
__global__ __launch_bounds__(256) void mm_kernel(const float* __restrict__ X,
    const float* __restrict__ wc, const float* __restrict__ tp,
    float* __restrict__ Y, float* __restrict__ pS, float* __restrict__ pQ, int o_base)
{
  __shared__ __align__(16) float wT[CI_PAD][64];
  __shared__ __align__(16) float tpr[CI_PAD];
  __shared__ float redS[4][64];
  __shared__ float redQ[4][64];
  const int tid = threadIdx.x;
  const int m0 = blockIdx.x << 8;
  const int b  = blockIdx.x >> 7;          // 128 blocks per batch
  for (int idx = tid; idx < CI_PAD*64; idx += 256){
    int c = idx >> 6, o = idx & 63;
    wT[c][o] = (c < CI_REAL) ? wc[(o_base + o)*CI_REAL + c] : 0.0f;
  }
  if (tid < CI_PAD) tpr[tid] = tp[b*68 + tid];
  __syncthreads();
  const int rg = tid >> 2, cg = tid & 3;
  const float* x0 = X + (size_t)(m0 + (rg<<2)) * LDX;
  float4 acc[4][4];
#pragma unroll
  for (int r=0;r<4;++r)
#pragma unroll
    for (int q=0;q<4;++q) acc[r][q] = make_float4(0.f,0.f,0.f,0.f);

  for (int c = 0; c < CI_PAD; c += 4){
    const float4 tpv = *reinterpret_cast<const float4*>(&tpr[c]);
    float4 xr[4];
#pragma unroll
    for (int r=0;r<4;++r){
      float4 xv = *reinterpret_cast<const float4*>(x0 + r*LDX + c);
      xr[r] = make_float4(xv.x+tpv.x, xv.y+tpv.y, xv.z+tpv.z, xv.w+tpv.w);
    }
#pragma unroll
    for (int cc=0; cc<4; ++cc){
      const float* wrow = &wT[c+cc][cg<<4];
      const float4 w0 = *reinterpret_cast<const float4*>(wrow);
      const float4 w1 = *reinterpret_cast<const float4*>(wrow+4);
      const float4 w2 = *reinterpret_cast<const float4*>(wrow+8);
      const float4 w3 = *reinterpret_cast<const float4*>(wrow+12);
#pragma unroll
      for (int r=0;r<4;++r){
        const float xs = (cc==0)?xr[r].x:((cc==1)?xr[r].y:((cc==2)?xr[r].z:xr[r].w));
        acc[r][0].x = fmaf(xs, w0.x, acc[r][0].x);
        acc[r][0].y = fmaf(xs, w0.y, acc[r][0].y);
        acc[r][0].z = fmaf(xs, w0.z, acc[r][0].z);
        acc[r][0].w = fmaf(xs, w0.w, acc[r][0].w);
        acc[r][1].x = fmaf(xs, w1.x, acc[r][1].x);
        acc[r][1].y = fmaf(xs, w1.y, acc[r][1].y);
        acc[r][1].z = fmaf(xs, w1.z, acc[r][1].z);
        acc[r][1].w = fmaf(xs, w1.w, acc[r][1].w);
        acc[r][2].x = fmaf(xs, w2.x, acc[r][2].x);
        acc[r][2].y = fmaf(xs, w2.y, acc[r][2].y);
        acc[r][2].z = fmaf(xs, w2.z, acc[r][2].z);
        acc[r][2].w = fmaf(xs, w2.w, acc[r][2].w);
        acc[r][3].x = fmaf(xs, w3.x, acc[r][3].x);
        acc[r][3].y = fmaf(xs, w3.y, acc[r][3].y);
        acc[r][3].z = fmaf(xs, w3.z, acc[r][3].z);
        acc[r][3].w = fmaf(xs, w3.w, acc[r][3].w);
      }
    }
  }
  // store Y
#pragma unroll
  for (int r=0;r<4;++r){
    float4* yp = reinterpret_cast<float4*>(Y + (size_t)(m0 + (rg<<2) + r)*64 + (cg<<4));
#pragma unroll
    for (int q=0;q<4;++q) yp[q] = acc[r][q];
  }
  // fused BN partials: per-thread sum/sumsq over its 4 rows, then shfl tree over row-groups
  float4 s[4], q2[4];
#pragma unroll
  for (int q=0;q<4;++q){
    float sx=0,sy=0,sz=0,sw=0, qx=0,qy=0,qz=0,qw=0;
#pragma unroll
    for (int r=0;r<4;++r){
      sx+=acc[r][q].x; qx+=acc[r][q].x*acc[r][q].x;
      sy+=acc[r][q].y; qy+=acc[r][q].y*acc[r][q].y;
      sz+=acc[r][q].z; qz+=acc[r][q].z*acc[r][q].z;
      sw+=acc[r][q].w; qw+=acc[r][q].w*acc[r][q].w;
    }
    s[q]=make_float4(sx,sy,sz,sw); q2[q]=make_float4(qx,qy,qz,qw);
  }
  const int lane = tid & 63, wv = tid >> 6;
#pragma unroll
  for (int off=32; off>=4; off>>=1){
#pragma unroll
    for (int q=0;q<4;++q){
      s[q].x  += __shfl_down(s[q].x,  off);
      s[q].y  += __shfl_down(s[q].y,  off);
      s[q].z  += __shfl_down(s[q].z,  off);
      s[q].w  += __shfl_down(s[q].w,  off);
      q2[q].x += __shfl_down(q2[q].x, off);
      q2[q].y += __shfl_down(q2[q].y, off);
      q2[q].z += __shfl_down(q2[q].z, off);
      q2[q].w += __shfl_down(q2[q].w, off);
    }
  }
  if (lane < 4){  // lane == cg
#pragma unroll
    for (int q=0;q<4;++q){
      redS[wv][lane*16 + q*4 + 0] = s[q].x;
      redS[wv][lane*16 + q*4 + 1] = s[q].y;
      redS[wv][lane*16 + q*4 + 2] = s[q].z;
      redS[wv][lane*16 + q*4 + 3] = s[q].w;
      redQ[wv][lane*16 + q*4 + 0] = q2[q].x;
      redQ[wv][lane*16 + q*4 + 1] = q2[q].y;
      redQ[wv][lane*16 + q*4 + 2] = q2[q].z;
      redQ[wv][lane*16 + q*4 + 3] = q2[q].w;
    }
  }
  __syncthreads();
  if (tid < 64){
    float a=0.f, bb=0.f;
#pragma unroll
    for (int w2=0; w2<4; ++w2){ a += redS[w2][tid]; bb += redQ[w2][tid]; }
    pS[(blockIdx.x<<6) + tid] = a;
    pQ[(blockIdx.x<<6) + tid] = bb;
  }
}

// ---------------- finalize BN stats -> scale/shift ----------------
__global__ __launch_bounds__(64) void finalize_kernel(const float* __restrict__ pS,
    const float* __restrict__ pQ, const float* __restrict__ g, const float* __restrict__ be,
    float* __restrict__ scale, float* __restrict__ shift, int nblk){
  const int o = threadIdx.x;
  float s=0.f, q=0.f;
  for (int i=0;i<nblk;++i){ s += pS[(i<<6)+o]; q += pQ[(i<<6)+o]; }
  const float inv_n = 1.0f/(float)Mc;        // 1/262144, exact pow2
  const float mu = s*inv_n;
  const float var = q*inv_n - mu*mu;
  const float rs = 1.0f/sqrtf(var + 1e-5f);
  const float sc = rs*g[o];
  scale[o] = sc;
  shift[o] = fmaf(-mu, sc, be[o]);
}

// ---------------- normalize + GELU (layers 0,1) ----------------
__global__ __launch_bounds__(256) void norm_kernel(const float4* __restrict__ Y,
    const float* __restrict__ scale, const float* __restrict__ shift,
    float4* __restrict__ Xo, int n4){
  int i = blockIdx.x*blockDim.x + threadIdx.x;
  const int stride = gridDim.x*blockDim.x;
  for (; i<n4; i+=stride){
    const int c = (i & 15) << 2;             // (i*4) % 64
    const float4 sc = *reinterpret_cast<const float4*>(scale + c);
    const float4 sh = *reinterpret_cast<const float4*>(shift + c);
    float4 y = Y[i];
    float4 o;
    o.x = gelu_f(fmaf(y.x, sc.x, sh.x));
    o.y = gelu_f(fmaf(y.y, sc.y, sh.y));
    o.z = gelu_f(fmaf(y.z, sc.z, sh.z));
    o.w = gelu_f(fmaf(y.w, sc.w, sh.w));
    Xo[i] = o;
  }
}

// ---------------- layer2: normalize + GELU + max over K -> new_points (B,128,S) ----------------
__global__ __launch_bounds__(256) void pool_kernel(const float* __restrict__ Y,
    const float* __restrict__ scale, const float* __restrict__ shift,
    float* __restrict__ out, int o_base){
  __shared__ float pool[32][65];
  const int tid = threadIdx.x;
  const int b  = blockIdx.x >> 5;
  const int s0 = (blockIdx.x & 31) << 5;     // 32 centroids per block
  const int c  = tid & 63;
  const int sl0 = tid >> 6;
  const float sc = scale[c], sh = shift[c];
  for (int sp=0; sp<8; ++sp){
    const int sl = (sp<<2) + sl0;
    const int s = s0 + sl;
    const float* yp = Y + ((size_t)((b<<10)+s)<<5)*64 + c;
    float mx = -1e30f;
#pragma unroll 4
    for (int k=0;k<32;++k){
      float v = yp[(size_t)(k<<6)];
      v = gelu_f(fmaf(v, sc, sh));
      mx = fmaxf(mx, v);
    }
    pool[sl][c] = mx;
  }
  __syncthreads();
  for (int p=0;p<8;++p){
    const int c2 = (p<<3) + (tid>>5);
    const int sl = tid & 31;
    out[((size_t)((b<<7) + o_base + c2)<<10) + s0 + sl] = pool[sl][c2];
  }
}

// ---------------- launch ----------------
extern "C" void kernel_launch(void* const* d_in, const int* in_sizes, int n_in,
                              void* d_out, int out_size, void* d_ws, size_t ws_size,
                              hipStream_t stream){
  const float* xyz     = (const float*)d_in[0];
  const float* points  = (const float*)d_in[1];
  const float* t_embed = (const float*)d_in[2];
  const float* wt0=(const float*)d_in[3],  *bt0=(const float*)d_in[4],  *wc0=(const float*)d_in[5];
  const float* g0 =(const float*)d_in[7],  *be0=(const float*)d_in[8];
  const float* wt1=(const float*)d_in[9],  *bt1=(const float*)d_in[10], *wc1=(const float*)d_in[11];
  const float* g1 =(const float*)d_in[13], *be1=(const float*)d_in[14];
  const float* wt2=(const float*)d_in[15], *bt2=(const float*)d_in[16], *wc2=(const float*)d_in[17];
  const float* g2 =(const float*)d_in[19], *be2=(const float*)d_in[20];

  float* out_xyz = (float*)d_out;                    // (B,S,3)
  float* out_pts = (float*)d_out + Bc*Sc*3;          // (B,128,S)

  // workspace layout (floats); total ~148.4 MB
  float* ws       = (float*)d_ws;
  float* tp       = ws + 0;            // 3*8*68 = 1632 (reserve 2048)
  float* pointsT  = ws + 2048;         // 8*4096*64 = 2097152
  int*   ballidx  = (int*)(ws + 2099200);   // 262144 ints
  float* X        = ws + 2361344;      // 262144*68 = 17825792
  float* Y        = ws + 20187136;     // 262144*64 = 16777216
  float* pS       = ws + 36964352;     // 1024*64
  float* pQ       = ws + 37029888;     // 1024*64
  float* scale    = ws + 37095424;     // 64
  float* shift    = ws + 37095488;     // 64

  tp_kernel<<<1, 256, 0, stream>>>(t_embed, wt0,bt0, wt1,bt1, wt2,bt2, tp);
  fps_kernel<<<Bc, 512, 0, stream>>>(xyz, out_xyz);
  transpose_kernel<<<dim3(64, Bc), 256, 0, stream>>>(points, pointsT);
  ball_kernel<<<(Bc*Sc)/4, 256, 0, stream>>>(xyz, out_xyz, ballidx);
  gather_kernel<<<Bc*Sc, 256, 0, stream>>>(xyz, out_xyz, pointsT, ballidx, X);

  // layer 0: ci=67 (pad 68), co=64
  mm_kernel<67,68,68><<<Mc/256, 256, 0, stream>>>(X, wc0, tp, Y, pS, pQ, 0);
  finalize_kernel<<<1, 64, 0, stream>>>(pS, pQ, g0, be0, scale, shift, Mc/256);
  norm_kernel<<<4096, 256, 0, stream>>>((const float4*)Y, scale, shift, (float4*)X, Mc*64/4);

  // layer 1: ci=64, co=64
  mm_kernel<64,64,64><<<Mc/256, 256, 0, stream>>>(X, wc1, tp + 544, Y, pS, pQ, 0);
  finalize_kernel<<<1, 64, 0, stream>>>(pS, pQ, g1, be1, scale, shift, Mc/256);
  norm_kernel<<<4096, 256, 0, stream>>>((const float4*)Y, scale, shift, (float4*)X, Mc*64/4);

  // layer 2: ci=64, co=128 in two 64-col halves, fused BN+GELU+maxpool
  mm_kernel<64,64,64><<<Mc/256, 256, 0, stream>>>(X, wc2, tp + 1088, Y, pS, pQ, 0);
  finalize_kernel<<<1, 64, 0, stream>>>(pS, pQ, g2, be2, scale, shift, Mc/256);
  pool_kernel<<<Bc*Sc/32, 256, 0, stream>>>(Y, scale, shift, out_pts, 0);

  mm_kernel<64,64,64><<<Mc/256, 256, 0, stream>>>(X, wc2, tp + 1088, Y, pS, pQ, 64);
  finalize_kernel<<<1, 64, 0, stream>>>(pS, pQ, g2+64, be2+64, scale, shift, Mc/256);
  pool_kernel<<<Bc*Sc/32, 256, 0, stream>>>(Y, scale, shift, out_pts, 64);
}

// Round 3
// 1319.352 us; speedup vs baseline: 2.5863x; 2.5863x over previous
//
#include <hip/hip_runtime.h>
#include <cmath>

// Problem constants (from reference setup_inputs)
#define Bc 8
#define Nc 4096
#define Sc 1024
#define Kc 32
#define Mc (Bc*Sc*Kc)   // 262144 rows

__device__ __forceinline__ float gelu_f(float x){
  return 0.5f*x*(1.0f + erff(x*0.70710678f));
}

// ---------------- tp MLP: tp[l][b][c] = gelu(t_embed[b]) @ wt_l.T + bt_l ----------------
__global__ __launch_bounds__(256) void tp_kernel(const float* __restrict__ t_embed,
    const float* __restrict__ wt0, const float* __restrict__ bt0,
    const float* __restrict__ wt1, const float* __restrict__ bt1,
    const float* __restrict__ wt2, const float* __restrict__ bt2,
    float* __restrict__ tp){
  __shared__ float ge[Bc*128];
  const int tid = threadIdx.x;
  for (int i = tid; i < Bc*128; i += 256){
    ge[i] = gelu_f(t_embed[i]);
  }
  __syncthreads();
  // layout: tp[(l*8 + b)*68 + c], pad c>=ci with 0
  for (int i = tid; i < 3*Bc*68; i += 256){
    int l = i / (Bc*68);
    int r = i - l*(Bc*68);
    int b = r / 68;
    int c = r - b*68;
    int ci = (l==0) ? 67 : 64;
    float v = 0.0f;
    if (c < ci){
      const float* wt = (l==0)?wt0:((l==1)?wt1:wt2);
      const float* bt = (l==0)?bt0:((l==1)?bt1:bt2);
      const float* w = wt + c*128;
      const float* g = ge + b*128;
      float acc = 0.0f;
      for (int t=0;t<128;++t) acc = fmaf(g[t], w[t], acc);
      v = acc + bt[c];
    }
    tp[i] = v;
  }
}

// ---------------- FPS v2: one block/batch, packed-u64 reduce, 1 barrier/iter ----------------
// Bitwise-exact vs numpy: ((dx*dx + dy*dy) + dz*dz), fmin, argmax tie -> lowest index.
__global__ __launch_bounds__(256) void fps_kernel(const float* __restrict__ xyz,
                                                  float* __restrict__ new_xyz){
  const int b = blockIdx.x;
  const int tid = threadIdx.x;
  const int lane = tid & 63;
  const int wv = tid >> 6;
  const float* xb = xyz + b*Nc*3;
  __shared__ float sx[Nc], sy[Nc], sz[Nc];     // 48 KB coord stash for winner lookup
  __shared__ unsigned long long skey[2][4];    // parity double-buffered wave keys
  float px[16], py[16], pz[16], dist[16];
#pragma unroll
  for (int j=0;j<16;++j){
    const int i = tid + (j<<8);
    const float x = xb[i*3+0], y = xb[i*3+1], z = xb[i*3+2];
    px[j]=x; py[j]=y; pz[j]=z;
    sx[i]=x; sy[i]=y; sz[i]=z;
    dist[j]=1e10f;
  }
  __syncthreads();
  int widx = 0;                                // deterministic start at index 0
  for (int it=0; it<Sc; ++it){
    const float cx = sx[widx], cy = sy[widx], cz = sz[widx];   // LDS broadcast
    if (tid==0){
      float* o = new_xyz + ((size_t)b*Sc + it)*3;
      o[0]=cx; o[1]=cy; o[2]=cz;
    }
    float bv = -1.0f; int bj = 0;
#pragma unroll
    for (int j=0;j<16;++j){
      // exact numpy order: ((dx*dx + dy*dy) + dz*dz), no FMA contraction
      const float dx=__fsub_rn(px[j],cx);
      const float dy=__fsub_rn(py[j],cy);
      const float dz=__fsub_rn(pz[j],cz);
      const float dd=__fadd_rn(__fadd_rn(__fmul_rn(dx,dx),__fmul_rn(dy,dy)),__fmul_rn(dz,dz));
      const float dn=fminf(dist[j],dd);
      dist[j]=dn;
      if (dn > bv){ bv=dn; bj=j; }            // strict > : lowest j (=lowest idx) on tie
    }
    // pack: high = dist bits (nonneg float -> monotone as uint), low = 4095 - idx (max -> min idx)
    const int bidx = tid + (bj<<8);
    unsigned long long key = ((unsigned long long)__float_as_uint(bv) << 32)
                           | (unsigned long long)(unsigned int)(4095 - bidx);
#pragma unroll
    for (int off=1; off<64; off<<=1){
      const unsigned long long ok = __shfl_xor(key, off);
      key = (ok > key) ? ok : key;
    }
    const int p = it & 1;
    if (lane==0) skey[p][wv] = key;
    __syncthreads();                           // single barrier per iteration
    const unsigned long long k0 = skey[p][0];
    const unsigned long long k1 = skey[p][1];
    const unsigned long long k2 = skey[p][2];
    const unsigned long long k3 = skey[p][3];
    unsigned long long ka = (k0>k1)?k0:k1;
    unsigned long long kb = (k2>k3)?k2:k3;
    ka = (ka>kb)?ka:kb;
    widx = 4095 - (int)(unsigned int)(ka & 0xFFFFFFFFull);
  }
}

// ---------------- points (B,C,N) -> pointsT (B,N,C) ----------------
__global__ __launch_bounds__(256) void transpose_kernel(const float* __restrict__ points,
                                                        float* __restrict__ pointsT){
  const int b = blockIdx.y;
  const int n0 = blockIdx.x << 6;
  __shared__ float tile[64][65];
  const int tid = threadIdx.x;
  const int sub = tid >> 6;      // 0..3
  const int ln  = tid & 63;
#pragma unroll 4
  for (int cp=0; cp<16; ++cp){
    int c = (cp<<2) + sub;
    tile[c][ln] = points[((size_t)(b*64+c))*Nc + n0 + ln];
  }
  __syncthreads();
#pragma unroll 4
  for (int np=0; np<16; ++np){
    int nl = (np<<2) + sub;
    pointsT[((size_t)(b*Nc + n0 + nl))*64 + ln] = tile[ln][nl];
  }
}

// ---------------- ball query: 1 wave per centroid ----------------
__global__ __launch_bounds__(256) void ball_kernel(const float* __restrict__ xyz,
    const float* __restrict__ new_xyz, int* __restrict__ ballidx){
  const int g = (blockIdx.x<<2) + (threadIdx.x>>6);   // centroid id in [0, B*S)
  const int lane = threadIdx.x & 63;
  const int w = threadIdx.x >> 6;
  const int b = g >> 10;
  const float* xb = xyz + b*Nc*3;
  const float cx = new_xyz[g*3+0];
  const float cy = new_xyz[g*3+1];
  const float cz = new_xyz[g*3+2];
  __shared__ int sidx[4][32];
  int total = 0;
  for (int base=0; base<Nc; base+=64){
    const int i = base + lane;
    float dx=__fsub_rn(cx, xb[i*3+0]);
    float dy=__fsub_rn(cy, xb[i*3+1]);
    float dz=__fsub_rn(cz, xb[i*3+2]);
    float sq=__fadd_rn(__fadd_rn(__fmul_rn(dx,dx),__fmul_rn(dy,dy)),__fmul_rn(dz,dz));
    bool hit = !(sq > 0.04f);                     // sqr <= R^2, matching reference exactly
    unsigned long long m = __ballot(hit);
    if (hit){
      int pos = total + (int)__popcll(m & ((1ull<<lane)-1ull));
      if (pos < 32) sidx[w][pos] = i;
    }
    total += (int)__popcll(m);
    if (total >= 32) break;
  }
  __syncthreads();  // waves diverge in loop trip count; also orders LDS writes before reads
  const int fill = (total < 32) ? total : 32;     // >=1 always (centroid itself is a hit)
  const int first = sidx[w][0];
  if (lane >= fill && lane < 32) sidx[w][lane] = first;
  if (lane < 32) ballidx[(g<<5)+lane] = sidx[w][lane];
}

// ---------------- gather + concat: X (M x 68), cols 0..2 rel xyz, 3..66 points, 67 pad=0 ----------------
__global__ __launch_bounds__(256) void gather_kernel(const float* __restrict__ xyz,
    const float* __restrict__ new_xyz, const float* __restrict__ pointsT,
    const int* __restrict__ ballidx, float* __restrict__ X){
  const int bs = blockIdx.x;
  const int b = bs >> 10;
  const int w = threadIdx.x >> 6;
  const int lane = threadIdx.x & 63;
  const float cx=new_xyz[bs*3+0], cy=new_xyz[bs*3+1], cz=new_xyz[bs*3+2];
  for (int k=w; k<32; k+=4){
    const int pidx = ballidx[(bs<<5)+k];
    const float* pt = pointsT + ((size_t)((b<<12)+pidx))*64;
    const float* xp = xyz + ((size_t)((b<<12)+pidx))*3;
    float* xr = X + (size_t)((bs<<5)+k)*68;
    float v;
    if      (lane==0) v = __fsub_rn(xp[0], cx);
    else if (lane==1) v = __fsub_rn(xp[1], cy);
    else if (lane==2) v = __fsub_rn(xp[2], cz);
    else              v = pt[lane-3];
    xr[lane] = v;
    if (lane < 4){
      int c = 64 + lane;
      xr[c] = (c<67) ? pt[c-3] : 0.0f;
    }
  }
}

// ---------------- 1x1 conv matmul + fused per-block BN partial sums ----------------
// y[m][o] = sum_c (x[m][c] + tp[b][c]) * wc[o_base+o][c]   (bc omitted: cancels in BN exactly)
template<int CI_REAL, int CI_PAD, int LDX>
__global__ __launch_bounds__(256) void mm_kernel(const float* __restrict__ X,
    const float* __restrict__ wc, const float* __restrict__ tp,
    float* __restrict__ Y, float* __restrict__ pS, float* __restrict__ pQ, int o_base)
{
  __shared__ __align__(16) float wT[CI_PAD][64];
  __shared__ __align__(16) float tpr[CI_PAD];
  __shared__ float redS[4][64];
  __shared__ float redQ[4][64];
  const int tid = threadIdx.x;
  const int m0 = blockIdx.x << 8;
  const int b  = blockIdx.x >> 7;          // 128 blocks per batch
  for (int idx = tid; idx < CI_PAD*64; idx += 256){
    int c = idx >> 6, o = idx & 63;
    wT[c][o] = (c < CI_REAL) ? wc[(o_base + o)*CI_REAL + c] : 0.0f;
  }
  if (tid < CI_PAD) tpr[tid] = tp[b*68 + tid];
  __syncthreads();
  const int rg = tid >> 2, cg = tid & 3;
  const float* x0 = X + (size_t)(m0 + (rg<<2)) * LDX;
  float4 acc[4][4];
#pragma unroll
  for (int r=0;r<4;++r)
#pragma unroll
    for (int q=0;q<4;++q) acc[r][q] = make_float4(0.f,0.f,0.f,0.f);

  for (int c = 0; c < CI_PAD; c += 4){
    const float4 tpv = *reinterpret_cast<const float4*>(&tpr[c]);
    float4 xr[4];
#pragma unroll
    for (int r=0;r<4;++r){
      float4 xv = *reinterpret_cast<const float4*>(x0 + r*LDX + c);
      xr[r] = make_float4(xv.x+tpv.x, xv.y+tpv.y, xv.z+tpv.z, xv.w+tpv.w);
    }
#pragma unroll
    for (int cc=0; cc<4; ++cc){
      const float* wrow = &wT[c+cc][cg<<4];
      const float4 w0 = *reinterpret_cast<const float4*>(wrow);
      const float4 w1 = *reinterpret_cast<const float4*>(wrow+4);
      const float4 w2 = *reinterpret_cast<const float4*>(wrow+8);
      const float4 w3 = *reinterpret_cast<const float4*>(wrow+12);
#pragma unroll
      for (int r=0;r<4;++r){
        const float xs = (cc==0)?xr[r].x:((cc==1)?xr[r].y:((cc==2)?xr[r].z:xr[r].w));
        acc[r][0].x = fmaf(xs, w0.x, acc[r][0].x);
        acc[r][0].y = fmaf(xs, w0.y, acc[r][0].y);
        acc[r][0].z = fmaf(xs, w0.z, acc[r][0].z);
        acc[r][0].w = fmaf(xs, w0.w, acc[r][0].w);
        acc[r][1].x = fmaf(xs, w1.x, acc[r][1].x);
        acc[r][1].y = fmaf(xs, w1.y, acc[r][1].y);
        acc[r][1].z = fmaf(xs, w1.z, acc[r][1].z);
        acc[r][1].w = fmaf(xs, w1.w, acc[r][1].w);
        acc[r][2].x = fmaf(xs, w2.x, acc[r][2].x);
        acc[r][2].y = fmaf(xs, w2.y, acc[r][2].y);
        acc[r][2].z = fmaf(xs, w2.z, acc[r][2].z);
        acc[r][2].w = fmaf(xs, w2.w, acc[r][2].w);
        acc[r][3].x = fmaf(xs, w3.x, acc[r][3].x);
        acc[r][3].y = fmaf(xs, w3.y, acc[r][3].y);
        acc[r][3].z = fmaf(xs, w3.z, acc[r][3].z);
        acc[r][3].w = fmaf(xs, w3.w, acc[r][3].w);
      }
    }
  }
  // store Y
#pragma unroll
  for (int r=0;r<4;++r){
    float4* yp = reinterpret_cast<float4*>(Y + (size_t)(m0 + (rg<<2) + r)*64 + (cg<<4));
#pragma unroll
    for (int q=0;q<4;++q) yp[q] = acc[r][q];
  }
  // fused BN partials: per-thread sum/sumsq over its 4 rows, then shfl tree over row-groups
  float4 s[4], q2[4];
#pragma unroll
  for (int q=0;q<4;++q){
    float sx=0,sy=0,sz=0,sw=0, qx=0,qy=0,qz=0,qw=0;
#pragma unroll
    for (int r=0;r<4;++r){
      sx+=acc[r][q].x; qx+=acc[r][q].x*acc[r][q].x;
      sy+=acc[r][q].y; qy+=acc[r][q].y*acc[r][q].y;
      sz+=acc[r][q].z; qz+=acc[r][q].z*acc[r][q].z;
      sw+=acc[r][q].w; qw+=acc[r][q].w*acc[r][q].w;
    }
    s[q]=make_float4(sx,sy,sz,sw); q2[q]=make_float4(qx,qy,qz,qw);
  }
  const int lane = tid & 63, wvv = tid >> 6;
#pragma unroll
  for (int off=32; off>=4; off>>=1){
#pragma unroll
    for (int q=0;q<4;++q){
      s[q].x  += __shfl_down(s[q].x,  off);
      s[q].y  += __shfl_down(s[q].y,  off);
      s[q].z  += __shfl_down(s[q].z,  off);
      s[q].w  += __shfl_down(s[q].w,  off);
      q2[q].x += __shfl_down(q2[q].x, off);
      q2[q].y += __shfl_down(q2[q].y, off);
      q2[q].z += __shfl_down(q2[q].z, off);
      q2[q].w += __shfl_down(q2[q].w, off);
    }
  }
  if (lane < 4){  // lane == cg
#pragma unroll
    for (int q=0;q<4;++q){
      redS[wvv][lane*16 + q*4 + 0] = s[q].x;
      redS[wvv][lane*16 + q*4 + 1] = s[q].y;
      redS[wvv][lane*16 + q*4 + 2] = s[q].z;
      redS[wvv][lane*16 + q*4 + 3] = s[q].w;
      redQ[wvv][lane*16 + q*4 + 0] = q2[q].x;
      redQ[wvv][lane*16 + q*4 + 1] = q2[q].y;
      redQ[wvv][lane*16 + q*4 + 2] = q2[q].z;
      redQ[wvv][lane*16 + q*4 + 3] = q2[q].w;
    }
  }
  __syncthreads();
  if (tid < 64){
    float a=0.f, bb=0.f;
#pragma unroll
    for (int w2=0; w2<4; ++w2){ a += redS[w2][tid]; bb += redQ[w2][tid]; }
    pS[(blockIdx.x<<6) + tid] = a;
    pQ[(blockIdx.x<<6) + tid] = bb;
  }
}

// ---------------- finalize BN stats -> scale/shift (parallel over 4 chunks x 64 ch) ----------------
__global__ __launch_bounds__(256) void finalize_kernel(const float* __restrict__ pS,
    const float* __restrict__ pQ, const float* __restrict__ g, const float* __restrict__ be,
    float* __restrict__ scale, float* __restrict__ shift, int nblk){
  __shared__ float rS[4][64], rQ[4][64];
  const int o = threadIdx.x & 63;
  const int ch = threadIdx.x >> 6;          // 4 chunks
  const int per = nblk >> 2;                // 256
  float s=0.f, q=0.f;
  const int i0 = ch*per;
#pragma unroll 4
  for (int i=0;i<per;++i){
    s += pS[((i0+i)<<6)+o];
    q += pQ[((i0+i)<<6)+o];
  }
  rS[ch][o]=s; rQ[ch][o]=q;
  __syncthreads();
  if (threadIdx.x < 64){
    float ss = rS[0][o]+rS[1][o]+rS[2][o]+rS[3][o];
    float qq = rQ[0][o]+rQ[1][o]+rQ[2][o]+rQ[3][o];
    const float inv_n = 1.0f/(float)Mc;
    const float mu = ss*inv_n;
    const float var = qq*inv_n - mu*mu;
    const float rs = 1.0f/sqrtf(var + 1e-5f);
    const float sc = rs*g[o];
    scale[o] = sc;
    shift[o] = fmaf(-mu, sc, be[o]);
  }
}

// ---------------- normalize + GELU (layers 0,1) ----------------
__global__ __launch_bounds__(256) void norm_kernel(const float4* __restrict__ Y,
    const float* __restrict__ scale, const float* __restrict__ shift,
    float4* __restrict__ Xo, int n4){
  int i = blockIdx.x*blockDim.x + threadIdx.x;
  const int stride = gridDim.x*blockDim.x;
  for (; i<n4; i+=stride){
    const int c = (i & 15) << 2;             // (i*4) % 64
    const float4 sc = *reinterpret_cast<const float4*>(scale + c);
    const float4 sh = *reinterpret_cast<const float4*>(shift + c);
    float4 y = Y[i];
    float4 o;
    o.x = gelu_f(fmaf(y.x, sc.x, sh.x));
    o.y = gelu_f(fmaf(y.y, sc.y, sh.y));
    o.z = gelu_f(fmaf(y.z, sc.z, sh.z));
    o.w = gelu_f(fmaf(y.w, sc.w, sh.w));
    Xo[i] = o;
  }
}

// ---------------- layer2: normalize + GELU + max over K -> new_points (B,128,S) ----------------
__global__ __launch_bounds__(256) void pool_kernel(const float* __restrict__ Y,
    const float* __restrict__ scale, const float* __restrict__ shift,
    float* __restrict__ out, int o_base){
  __shared__ float pool[32][65];
  const int tid = threadIdx.x;
  const int b  = blockIdx.x >> 5;
  const int s0 = (blockIdx.x & 31) << 5;     // 32 centroids per block
  const int c  = tid & 63;
  const int sl0 = tid >> 6;
  const float sc = scale[c], sh = shift[c];
  for (int sp=0; sp<8; ++sp){
    const int sl = (sp<<2) + sl0;
    const int s = s0 + sl;
    const float* yp = Y + ((size_t)((b<<10)+s)<<5)*64 + c;
    float mx = -1e30f;
#pragma unroll 4
    for (int k=0;k<32;++k){
      float v = yp[(size_t)(k<<6)];
      v = gelu_f(fmaf(v, sc, sh));
      mx = fmaxf(mx, v);
    }
    pool[sl][c] = mx;
  }
  __syncthreads();
  for (int p=0;p<8;++p){
    const int c2 = (p<<3) + (tid>>5);
    const int sl = tid & 31;
    out[((size_t)((b<<7) + o_base + c2)<<10) + s0 + sl] = pool[sl][c2];
  }
}

// ---------------- launch ----------------
extern "C" void kernel_launch(void* const* d_in, const int* in_sizes, int n_in,
                              void* d_out, int out_size, void* d_ws, size_t ws_size,
                              hipStream_t stream){
  const float* xyz     = (const float*)d_in[0];
  const float* points  = (const float*)d_in[1];
  const float* t_embed = (const float*)d_in[2];
  const float* wt0=(const float*)d_in[3],  *bt0=(const float*)d_in[4],  *wc0=(const float*)d_in[5];
  const float* g0 =(const float*)d_in[7],  *be0=(const float*)d_in[8];
  const float* wt1=(const float*)d_in[9],  *bt1=(const float*)d_in[10], *wc1=(const float*)d_in[11];
  const float* g1 =(const float*)d_in[13], *be1=(const float*)d_in[14];
  const float* wt2=(const float*)d_in[15], *bt2=(const float*)d_in[16], *wc2=(const float*)d_in[17];
  const float* g2 =(const float*)d_in[19], *be2=(const float*)d_in[20];

  float* out_xyz = (float*)d_out;                    // (B,S,3)
  float* out_pts = (float*)d_out + Bc*Sc*3;          // (B,128,S)

  // workspace layout (floats); total ~148.4 MB
  float* ws       = (float*)d_ws;
  float* tp       = ws + 0;            // 3*8*68 = 1632 (reserve 2048)
  float* pointsT  = ws + 2048;         // 8*4096*64 = 2097152
  int*   ballidx  = (int*)(ws + 2099200);   // 262144 ints
  float* X        = ws + 2361344;      // 262144*68 = 17825792
  float* Y        = ws + 20187136;     // 262144*64 = 16777216
  float* pS       = ws + 36964352;     // 1024*64
  float* pQ       = ws + 37029888;     // 1024*64
  float* scale    = ws + 37095424;     // 64
  float* shift    = ws + 37095488;     // 64

  tp_kernel<<<1, 256, 0, stream>>>(t_embed, wt0,bt0, wt1,bt1, wt2,bt2, tp);
  fps_kernel<<<Bc, 256, 0, stream>>>(xyz, out_xyz);
  transpose_kernel<<<dim3(64, Bc), 256, 0, stream>>>(points, pointsT);
  ball_kernel<<<(Bc*Sc)/4, 256, 0, stream>>>(xyz, out_xyz, ballidx);
  gather_kernel<<<Bc*Sc, 256, 0, stream>>>(xyz, out_xyz, pointsT, ballidx, X);

  // layer 0: ci=67 (pad 68), co=64
  mm_kernel<67,68,68><<<Mc/256, 256, 0, stream>>>(X, wc0, tp, Y, pS, pQ, 0);
  finalize_kernel<<<1, 256, 0, stream>>>(pS, pQ, g0, be0, scale, shift, Mc/256);
  norm_kernel<<<4096, 256, 0, stream>>>((const float4*)Y, scale, shift, (float4*)X, Mc*64/4);

  // layer 1: ci=64, co=64
  mm_kernel<64,64,64><<<Mc/256, 256, 0, stream>>>(X, wc1, tp + 544, Y, pS, pQ, 0);
  finalize_kernel<<<1, 256, 0, stream>>>(pS, pQ, g1, be1, scale, shift, Mc/256);
  norm_kernel<<<4096, 256, 0, stream>>>((const float4*)Y, scale, shift, (float4*)X, Mc*64/4);

  // layer 2: ci=64, co=128 in two 64-col halves, fused BN+GELU+maxpool
  mm_kernel<64,64,64><<<Mc/256, 256, 0, stream>>>(X, wc2, tp + 1088, Y, pS, pQ, 0);
  finalize_kernel<<<1, 256, 0, stream>>>(pS, pQ, g2, be2, scale, shift, Mc/256);
  pool_kernel<<<Bc*Sc/32, 256, 0, stream>>>(Y, scale, shift, out_pts, 0);

  mm_kernel<64,64,64><<<Mc/256, 256, 0, stream>>>(X, wc2, tp + 1088, Y, pS, pQ, 64);
  finalize_kernel<<<1, 256, 0, stream>>>(pS, pQ, g2+64, be2+64, scale, shift, Mc/256);
  pool_kernel<<<Bc*Sc/32, 256, 0, stream>>>(Y, scale, shift, out_pts, 64);
}

// Round 4
// 1311.597 us; speedup vs baseline: 2.6016x; 1.0059x over previous
//
#include <hip/hip_runtime.h>
#include <cmath>

// Problem constants (from reference setup_inputs)
#define Bc 8
#define Nc 4096
#define Sc 1024
#define Kc 32
#define Mc (Bc*Sc*Kc)   // 262144 rows

typedef float v2f __attribute__((ext_vector_type(2)));

__device__ __forceinline__ float gelu_f(float x){
  return 0.5f*x*(1.0f + erff(x*0.70710678f));
}

// Packed f32 ops via inline asm: per-element IEEE RN, immune to FMA contraction.
__device__ __forceinline__ v2f pk_add(v2f a, v2f b){
  v2f d; asm("v_pk_add_f32 %0, %1, %2" : "=v"(d) : "v"(a), "v"(b)); return d;
}
__device__ __forceinline__ v2f pk_mul(v2f a, v2f b){
  v2f d; asm("v_pk_mul_f32 %0, %1, %2" : "=v"(d) : "v"(a), "v"(b)); return d;
}

// DPP reduction steps (VALU-speed cross-lane). row_ror:n = 0x120|n.
#define ROR_MAXF(v, n) { int _t = __builtin_amdgcn_update_dpp(__float_as_int(v), __float_as_int(v), 0x120|(n), 0xF, 0xF, false); \
                         v = fmaxf(v, __int_as_float(_t)); }
#define BC15_MAXF(v)   { int _t = __builtin_amdgcn_update_dpp(__float_as_int(v), __float_as_int(v), 0x142, 0xA, 0xF, false); \
                         v = fmaxf(v, __int_as_float(_t)); }
#define BC31_MAXF(v)   { int _t = __builtin_amdgcn_update_dpp(__float_as_int(v), __float_as_int(v), 0x143, 0xC, 0xF, false); \
                         v = fmaxf(v, __int_as_float(_t)); }
#define ROR_MINU(v, n) { unsigned _t = (unsigned)__builtin_amdgcn_update_dpp((int)(v), (int)(v), 0x120|(n), 0xF, 0xF, false); \
                         v = (v < _t) ? v : _t; }
#define BC15_MINU(v)   { unsigned _t = (unsigned)__builtin_amdgcn_update_dpp((int)(v), (int)(v), 0x142, 0xA, 0xF, false); \
                         v = (v < _t) ? v : _t; }
#define BC31_MINU(v)   { unsigned _t = (unsigned)__builtin_amdgcn_update_dpp((int)(v), (int)(v), 0x143, 0xC, 0xF, false); \
                         v = (v < _t) ? v : _t; }

// ---------------- tp MLP: tp[l][b][c] = gelu(t_embed[b]) @ wt_l.T + bt_l ----------------
__global__ __launch_bounds__(256) void tp_kernel(const float* __restrict__ t_embed,
    const float* __restrict__ wt0, const float* __restrict__ bt0,
    const float* __restrict__ wt1, const float* __restrict__ bt1,
    const float* __restrict__ wt2, const float* __restrict__ bt2,
    float* __restrict__ tp){
  __shared__ float ge[Bc*128];
  const int tid = threadIdx.x;
  for (int i = tid; i < Bc*128; i += 256){
    ge[i] = gelu_f(t_embed[i]);
  }
  __syncthreads();
  // layout: tp[(l*8 + b)*68 + c], pad c>=ci with 0
  for (int i = tid; i < 3*Bc*68; i += 256){
    int l = i / (Bc*68);
    int r = i - l*(Bc*68);
    int b = r / 68;
    int c = r - b*68;
    int ci = (l==0) ? 67 : 64;
    float v = 0.0f;
    if (c < ci){
      const float* wt = (l==0)?wt0:((l==1)?wt1:wt2);
      const float* bt = (l==0)?bt0:((l==1)?bt1:bt2);
      const float* w = wt + c*128;
      const float* g = ge + b*128;
      float acc = 0.0f;
      for (int t=0;t<128;++t) acc = fmaf(g[t], w[t], acc);
      v = acc + bt[c];
    }
    tp[i] = v;
  }
}

// ---------------- FPS v3: DPP chains, pk-f32 update, 1 barrier/iter ----------------
// Bitwise-exact vs numpy: d = ((dx*dx + dy*dy) + dz*dz); dist = fmin(dist, d);
// argmax with first-index tie-break.
__global__ __launch_bounds__(256) void fps_kernel(const float* __restrict__ xyz,
                                                  float* __restrict__ new_xyz){
  const int b = blockIdx.x;
  const int tid = threadIdx.x;
  const int lane = tid & 63;
  const int wv = tid >> 6;
  const float* xb = xyz + b*Nc*3;
  __shared__ float sx[Nc], sy[Nc], sz[Nc];       // 48 KB coord stash
  __shared__ __align__(16) float    sMV[2][4];   // parity-buffered wave maxima
  __shared__ __align__(16) unsigned sIV[2][4];   // parity-buffered wave argmin idx
  v2f px2[8], py2[8], pz2[8], dist2[8];
#pragma unroll
  for (int k=0;k<8;++k){
    const int i0 = tid + (2*k)*256;
    const int i1 = tid + (2*k+1)*256;
    const float x0=xb[i0*3+0], y0=xb[i0*3+1], z0=xb[i0*3+2];
    const float x1=xb[i1*3+0], y1=xb[i1*3+1], z1=xb[i1*3+2];
    px2[k].x=x0; px2[k].y=x1; py2[k].x=y0; py2[k].y=y1; pz2[k].x=z0; pz2[k].y=z1;
    sx[i0]=x0; sy[i0]=y0; sz[i0]=z0;
    sx[i1]=x1; sy[i1]=y1; sz[i1]=z1;
    dist2[k].x=1e10f; dist2[k].y=1e10f;
  }
  __syncthreads();
  int widx = 0;                                  // deterministic start at index 0
  for (int it=0; it<Sc; ++it){
    const float cx=sx[widx], cy=sy[widx], cz=sz[widx];   // LDS broadcast
    if (tid==0){
      float* o = new_xyz + ((size_t)b*Sc + it)*3;
      o[0]=cx; o[1]=cy; o[2]=cz;
    }
    v2f ncx, ncy, ncz;
    ncx.x=-cx; ncx.y=-cx; ncy.x=-cy; ncy.y=-cy; ncz.x=-cz; ncz.y=-cz;
    float bvx=-1.0f, bvy=-1.0f;
#pragma unroll
    for (int k=0;k<8;++k){
      const v2f dx = pk_add(px2[k], ncx);        // x + (-c) == x - c bitwise
      const v2f dy = pk_add(py2[k], ncy);
      const v2f dz = pk_add(pz2[k], ncz);
      const v2f dd = pk_add(pk_add(pk_mul(dx,dx), pk_mul(dy,dy)), pk_mul(dz,dz));
      v2f dn;
      dn.x = fminf(dist2[k].x, dd.x);
      dn.y = fminf(dist2[k].y, dd.y);
      dist2[k] = dn;
      bvx = fmaxf(bvx, dn.x);
      bvy = fmaxf(bvy, dn.y);
    }
    float mv = fmaxf(bvx, bvy);
    // wave max: 4x ror + bcast15 + bcast31, then lane63 -> SGPR broadcast
    ROR_MAXF(mv,1); ROR_MAXF(mv,2); ROR_MAXF(mv,4); ROR_MAXF(mv,8);
    BC15_MAXF(mv); BC31_MAXF(mv);
    mv = __int_as_float(__builtin_amdgcn_readlane(__float_as_int(mv), 63));
    // resolve lowest point-index with dist == wave max (ascending => min)
    unsigned iv = 0xFFFFFFFFu;
#pragma unroll
    for (int k=0;k<8;++k){
      const unsigned c0 = (dist2[k].x == mv) ? (unsigned)(tid + (2*k  )*256) : 0xFFFFFFFFu;
      const unsigned c1 = (dist2[k].y == mv) ? (unsigned)(tid + (2*k+1)*256) : 0xFFFFFFFFu;
      iv = (iv < c0) ? iv : c0;
      iv = (iv < c1) ? iv : c1;
    }
    // wave min-index chain
    ROR_MINU(iv,1); ROR_MINU(iv,2); ROR_MINU(iv,4); ROR_MINU(iv,8);
    BC15_MINU(iv); BC31_MINU(iv);
    iv = (unsigned)__builtin_amdgcn_readlane((int)iv, 63);
    const int p = it & 1;
    if (lane==0){ sMV[p][wv] = mv; sIV[p][wv] = iv; }
    __syncthreads();                             // single barrier per iteration
    const float4 m4 = *reinterpret_cast<const float4*>(&sMV[p][0]);
    const uint4  i4 = *reinterpret_cast<const uint4*>(&sIV[p][0]);
    const float bm = fmaxf(fmaxf(m4.x,m4.y), fmaxf(m4.z,m4.w));
    const unsigned v0 = (m4.x==bm)? i4.x : 0xFFFFFFFFu;
    const unsigned v1 = (m4.y==bm)? i4.y : 0xFFFFFFFFu;
    const unsigned v2 = (m4.z==bm)? i4.z : 0xFFFFFFFFu;
    const unsigned v3 = (m4.w==bm)? i4.w : 0xFFFFFFFFu;
    unsigned wmin = (v0<v1)?v0:v1;
    const unsigned wmin2 = (v2<v3)?v2:v3;
    wmin = (wmin<wmin2)?wmin:wmin2;
    widx = (int)wmin;
  }
}

// ---------------- points (B,C,N) -> pointsT (B,N,C) ----------------
__global__ __launch_bounds__(256) void transpose_kernel(const float* __restrict__ points,
                                                        float* __restrict__ pointsT){
  const int b = blockIdx.y;
  const int n0 = blockIdx.x << 6;
  __shared__ float tile[64][65];
  const int tid = threadIdx.x;
  const int sub = tid >> 6;      // 0..3
  const int ln  = tid & 63;
#pragma unroll 4
  for (int cp=0; cp<16; ++cp){
    int c = (cp<<2) + sub;
    tile[c][ln] = points[((size_t)(b*64+c))*Nc + n0 + ln];
  }
  __syncthreads();
#pragma unroll 4
  for (int np=0; np<16; ++np){
    int nl = (np<<2) + sub;
    pointsT[((size_t)(b*Nc + n0 + nl))*64 + ln] = tile[ln][nl];
  }
}

// ---------------- ball query: 1 wave per centroid ----------------
__global__ __launch_bounds__(256) void ball_kernel(const float* __restrict__ xyz,
    const float* __restrict__ new_xyz, int* __restrict__ ballidx){
  const int g = (blockIdx.x<<2) + (threadIdx.x>>6);   // centroid id in [0, B*S)
  const int lane = threadIdx.x & 63;
  const int w = threadIdx.x >> 6;
  const int b = g >> 10;
  const float* xb = xyz + b*Nc*3;
  const float cx = new_xyz[g*3+0];
  const float cy = new_xyz[g*3+1];
  const float cz = new_xyz[g*3+2];
  __shared__ int sidx[4][32];
  int total = 0;
  for (int base=0; base<Nc; base+=64){
    const int i = base + lane;
    float dx=__fsub_rn(cx, xb[i*3+0]);
    float dy=__fsub_rn(cy, xb[i*3+1]);
    float dz=__fsub_rn(cz, xb[i*3+2]);
    float sq=__fadd_rn(__fadd_rn(__fmul_rn(dx,dx),__fmul_rn(dy,dy)),__fmul_rn(dz,dz));
    bool hit = !(sq > 0.04f);                     // sqr <= R^2, matching reference exactly
    unsigned long long m = __ballot(hit);
    if (hit){
      int pos = total + (int)__popcll(m & ((1ull<<lane)-1ull));
      if (pos < 32) sidx[w][pos] = i;
    }
    total += (int)__popcll(m);
    if (total >= 32) break;
  }
  __syncthreads();  // waves diverge in loop trip count; also orders LDS writes before reads
  const int fill = (total < 32) ? total : 32;     // >=1 always (centroid itself is a hit)
  const int first = sidx[w][0];
  if (lane >= fill && lane < 32) sidx[w][lane] = first;
  if (lane < 32) ballidx[(g<<5)+lane] = sidx[w][lane];
}

// ---------------- gather + concat: X (M x 68), cols 0..2 rel xyz, 3..66 points, 67 pad=0 ----------------
__global__ __launch_bounds__(256) void gather_kernel(const float* __restrict__ xyz,
    const float* __restrict__ new_xyz, const float* __restrict__ pointsT,
    const int* __restrict__ ballidx, float* __restrict__ X){
  const int bs = blockIdx.x;
  const int b = bs >> 10;
  const int w = threadIdx.x >> 6;
  const int lane = threadIdx.x & 63;
  const float cx=new_xyz[bs*3+0], cy=new_xyz[bs*3+1], cz=new_xyz[bs*3+2];
  for (int k=w; k<32; k+=4){
    const int pidx = ballidx[(bs<<5)+k];
    const float* pt = pointsT + ((size_t)((b<<12)+pidx))*64;
    const float* xp = xyz + ((size_t)((b<<12)+pidx))*3;
    float* xr = X + (size_t)((bs<<5)+k)*68;
    float v;
    if      (lane==0) v = __fsub_rn(xp[0], cx);
    else if (lane==1) v = __fsub_rn(xp[1], cy);
    else if (lane==2) v = __fsub_rn(xp[2], cz);
    else              v = pt[lane-3];
    xr[lane] = v;
    if (lane < 4){
      int c = 64 + lane;
      xr[c] = (c<67) ? pt[c-3] : 0.0f;
    }
  }
}

// ---------------- 1x1 conv matmul + fused per-block BN partial sums ----------------
// y[m][o] = sum_c (x[m][c] + tp[b][c]) * wc[o_base+o][c]   (bc omitted: cancels in BN exactly)
template<int CI_REAL, int CI_PAD, int LDX>
__global__ __launch_bounds__(256) void mm_kernel(const float* __restrict__ X,
    const float* __restrict__ wc, const float* __restrict__ tp,
    float* __restrict__ Y, float* __restrict__ pS, float* __restrict__ pQ, int o_base)
{
  __shared__ __align__(16) float wT[CI_PAD][64];
  __shared__ __align__(16) float tpr[CI_PAD];
  __shared__ float redS[4][64];
  __shared__ float redQ[4][64];
  const int tid = threadIdx.x;
  const int m0 = blockIdx.x << 8;
  const int b  = blockIdx.x >> 7;          // 128 blocks per batch
  for (int idx = tid; idx < CI_PAD*64; idx += 256){
    int c = idx >> 6, o = idx & 63;
    wT[c][o] = (c < CI_REAL) ? wc[(o_base + o)*CI_REAL + c] : 0.0f;
  }
  if (tid < CI_PAD) tpr[tid] = tp[b*68 + tid];
  __syncthreads();
  const int rg = tid >> 2, cg = tid & 3;
  const float* x0 = X + (size_t)(m0 + (rg<<2)) * LDX;
  float4 acc[4][4];
#pragma unroll
  for (int r=0;r<4;++r)
#pragma unroll
    for (int q=0;q<4;++q) acc[r][q] = make_float4(0.f,0.f,0.f,0.f);

  for (int c = 0; c < CI_PAD; c += 4){
    const float4 tpv = *reinterpret_cast<const float4*>(&tpr[c]);
    float4 xr[4];
#pragma unroll
    for (int r=0;r<4;++r){
      float4 xv = *reinterpret_cast<const float4*>(x0 + r*LDX + c);
      xr[r] = make_float4(xv.x+tpv.x, xv.y+tpv.y, xv.z+tpv.z, xv.w+tpv.w);
    }
#pragma unroll
    for (int cc=0; cc<4; ++cc){
      const float* wrow = &wT[c+cc][cg<<4];
      const float4 w0 = *reinterpret_cast<const float4*>(wrow);
      const float4 w1 = *reinterpret_cast<const float4*>(wrow+4);
      const float4 w2 = *reinterpret_cast<const float4*>(wrow+8);
      const float4 w3 = *reinterpret_cast<const float4*>(wrow+12);
#pragma unroll
      for (int r=0;r<4;++r){
        const float xs = (cc==0)?xr[r].x:((cc==1)?xr[r].y:((cc==2)?xr[r].z:xr[r].w));
        acc[r][0].x = fmaf(xs, w0.x, acc[r][0].x);
        acc[r][0].y = fmaf(xs, w0.y, acc[r][0].y);
        acc[r][0].z = fmaf(xs, w0.z, acc[r][0].z);
        acc[r][0].w = fmaf(xs, w0.w, acc[r][0].w);
        acc[r][1].x = fmaf(xs, w1.x, acc[r][1].x);
        acc[r][1].y = fmaf(xs, w1.y, acc[r][1].y);
        acc[r][1].z = fmaf(xs, w1.z, acc[r][1].z);
        acc[r][1].w = fmaf(xs, w1.w, acc[r][1].w);
        acc[r][2].x = fmaf(xs, w2.x, acc[r][2].x);
        acc[r][2].y = fmaf(xs, w2.y, acc[r][2].y);
        acc[r][2].z = fmaf(xs, w2.z, acc[r][2].z);
        acc[r][2].w = fmaf(xs, w2.w, acc[r][2].w);
        acc[r][3].x = fmaf(xs, w3.x, acc[r][3].x);
        acc[r][3].y = fmaf(xs, w3.y, acc[r][3].y);
        acc[r][3].z = fmaf(xs, w3.z, acc[r][3].z);
        acc[r][3].w = fmaf(xs, w3.w, acc[r][3].w);
      }
    }
  }
  // store Y
#pragma unroll
  for (int r=0;r<4;++r){
    float4* yp = reinterpret_cast<float4*>(Y + (size_t)(m0 + (rg<<2) + r)*64 + (cg<<4));
#pragma unroll
    for (int q=0;q<4;++q) yp[q] = acc[r][q];
  }
  // fused BN partials: per-thread sum/sumsq over its 4 rows, then shfl tree over row-groups
  float4 s[4], q2[4];
#pragma unroll
  for (int q=0;q<4;++q){
    float sx=0,sy=0,sz=0,sw=0, qx=0,qy=0,qz=0,qw=0;
#pragma unroll
    for (int r=0;r<4;++r){
      sx+=acc[r][q].x; qx+=acc[r][q].x*acc[r][q].x;
      sy+=acc[r][q].y; qy+=acc[r][q].y*acc[r][q].y;
      sz+=acc[r][q].z; qz+=acc[r][q].z*acc[r][q].z;
      sw+=acc[r][q].w; qw+=acc[r][q].w*acc[r][q].w;
    }
    s[q]=make_float4(sx,sy,sz,sw); q2[q]=make_float4(qx,qy,qz,qw);
  }
  const int lane = tid & 63, wvv = tid >> 6;
#pragma unroll
  for (int off=32; off>=4; off>>=1){
#pragma unroll
    for (int q=0;q<4;++q){
      s[q].x  += __shfl_down(s[q].x,  off);
      s[q].y  += __shfl_down(s[q].y,  off);
      s[q].z  += __shfl_down(s[q].z,  off);
      s[q].w  += __shfl_down(s[q].w,  off);
      q2[q].x += __shfl_down(q2[q].x, off);
      q2[q].y += __shfl_down(q2[q].y, off);
      q2[q].z += __shfl_down(q2[q].z, off);
      q2[q].w += __shfl_down(q2[q].w, off);
    }
  }
  if (lane < 4){  // lane == cg
#pragma unroll
    for (int q=0;q<4;++q){
      redS[wvv][lane*16 + q*4 + 0] = s[q].x;
      redS[wvv][lane*16 + q*4 + 1] = s[q].y;
      redS[wvv][lane*16 + q*4 + 2] = s[q].z;
      redS[wvv][lane*16 + q*4 + 3] = s[q].w;
      redQ[wvv][lane*16 + q*4 + 0] = q2[q].x;
      redQ[wvv][lane*16 + q*4 + 1] = q2[q].y;
      redQ[wvv][lane*16 + q*4 + 2] = q2[q].z;
      redQ[wvv][lane*16 + q*4 + 3] = q2[q].w;
    }
  }
  __syncthreads();
  if (tid < 64){
    float a=0.f, bb=0.f;
#pragma unroll
    for (int w2=0; w2<4; ++w2){ a += redS[w2][tid]; bb += redQ[w2][tid]; }
    pS[(blockIdx.x<<6) + tid] = a;
    pQ[(blockIdx.x<<6) + tid] = bb;
  }
}

// ---------------- finalize BN stats -> scale/shift (parallel over 4 chunks x 64 ch) ----------------
__global__ __launch_bounds__(256) void finalize_kernel(const float* __restrict__ pS,
    const float* __restrict__ pQ, const float* __restrict__ g, const float* __restrict__ be,
    float* __restrict__ scale, float* __restrict__ shift, int nblk){
  __shared__ float rS[4][64], rQ[4][64];
  const int o = threadIdx.x & 63;
  const int ch = threadIdx.x >> 6;          // 4 chunks
  const int per = nblk >> 2;                // 256
  float s=0.f, q=0.f;
  const int i0 = ch*per;
#pragma unroll 4
  for (int i=0;i<per;++i){
    s += pS[((i0+i)<<6)+o];
    q += pQ[((i0+i)<<6)+o];
  }
  rS[ch][o]=s; rQ[ch][o]=q;
  __syncthreads();
  if (threadIdx.x < 64){
    float ss = rS[0][o]+rS[1][o]+rS[2][o]+rS[3][o];
    float qq = rQ[0][o]+rQ[1][o]+rQ[2][o]+rQ[3][o];
    const float inv_n = 1.0f/(float)Mc;
    const float mu = ss*inv_n;
    const float var = qq*inv_n - mu*mu;
    const float rs = 1.0f/sqrtf(var + 1e-5f);
    const float sc = rs*g[o];
    scale[o] = sc;
    shift[o] = fmaf(-mu, sc, be[o]);
  }
}

// ---------------- normalize + GELU (layers 0,1) ----------------
__global__ __launch_bounds__(256) void norm_kernel(const float4* __restrict__ Y,
    const float* __restrict__ scale, const float* __restrict__ shift,
    float4* __restrict__ Xo, int n4){
  int i = blockIdx.x*blockDim.x + threadIdx.x;
  const int stride = gridDim.x*blockDim.x;
  for (; i<n4; i+=stride){
    const int c = (i & 15) << 2;             // (i*4) % 64
    const float4 sc = *reinterpret_cast<const float4*>(scale + c);
    const float4 sh = *reinterpret_cast<const float4*>(shift + c);
    float4 y = Y[i];
    float4 o;
    o.x = gelu_f(fmaf(y.x, sc.x, sh.x));
    o.y = gelu_f(fmaf(y.y, sc.y, sh.y));
    o.z = gelu_f(fmaf(y.z, sc.z, sh.z));
    o.w = gelu_f(fmaf(y.w, sc.w, sh.w));
    Xo[i] = o;
  }
}

// ---------------- layer2: normalize + GELU + max over K -> new_points (B,128,S) ----------------
__global__ __launch_bounds__(256) void pool_kernel(const float* __restrict__ Y,
    const float* __restrict__ scale, const float* __restrict__ shift,
    float* __restrict__ out, int o_base){
  __shared__ float pool[32][65];
  const int tid = threadIdx.x;
  const int b  = blockIdx.x >> 5;
  const int s0 = (blockIdx.x & 31) << 5;     // 32 centroids per block
  const int c  = tid & 63;
  const int sl0 = tid >> 6;
  const float sc = scale[c], sh = shift[c];
  for (int sp=0; sp<8; ++sp){
    const int sl = (sp<<2) + sl0;
    const int s = s0 + sl;
    const float* yp = Y + ((size_t)((b<<10)+s)<<5)*64 + c;
    float mx = -1e30f;
#pragma unroll 4
    for (int k=0;k<32;++k){
      float v = yp[(size_t)(k<<6)];
      v = gelu_f(fmaf(v, sc, sh));
      mx = fmaxf(mx, v);
    }
    pool[sl][c] = mx;
  }
  __syncthreads();
  for (int p=0;p<8;++p){
    const int c2 = (p<<3) + (tid>>5);
    const int sl = tid & 31;
    out[((size_t)((b<<7) + o_base + c2)<<10) + s0 + sl] = pool[sl][c2];
  }
}

// ---------------- launch ----------------
extern "C" void kernel_launch(void* const* d_in, const int* in_sizes, int n_in,
                              void* d_out, int out_size, void* d_ws, size_t ws_size,
                              hipStream_t stream){
  const float* xyz     = (const float*)d_in[0];
  const float* points  = (const float*)d_in[1];
  const float* t_embed = (const float*)d_in[2];
  const float* wt0=(const float*)d_in[3],  *bt0=(const float*)d_in[4],  *wc0=(const float*)d_in[5];
  const float* g0 =(const float*)d_in[7],  *be0=(const float*)d_in[8];
  const float* wt1=(const float*)d_in[9],  *bt1=(const float*)d_in[10], *wc1=(const float*)d_in[11];
  const float* g1 =(const float*)d_in[13], *be1=(const float*)d_in[14];
  const float* wt2=(const float*)d_in[15], *bt2=(const float*)d_in[16], *wc2=(const float*)d_in[17];
  const float* g2 =(const float*)d_in[19], *be2=(const float*)d_in[20];

  float* out_xyz = (float*)d_out;                    // (B,S,3)
  float* out_pts = (float*)d_out + Bc*Sc*3;          // (B,128,S)

  // workspace layout (floats); total ~148.4 MB
  float* ws       = (float*)d_ws;
  float* tp       = ws + 0;            // 3*8*68 = 1632 (reserve 2048)
  float* pointsT  = ws + 2048;         // 8*4096*64 = 2097152
  int*   ballidx  = (int*)(ws + 2099200);   // 262144 ints
  float* X        = ws + 2361344;      // 262144*68 = 17825792
  float* Y        = ws + 20187136;     // 262144*64 = 16777216
  float* pS       = ws + 36964352;     // 1024*64
  float* pQ       = ws + 37029888;     // 1024*64
  float* scale    = ws + 37095424;     // 64
  float* shift    = ws + 37095488;     // 64

  tp_kernel<<<1, 256, 0, stream>>>(t_embed, wt0,bt0, wt1,bt1, wt2,bt2, tp);
  fps_kernel<<<Bc, 256, 0, stream>>>(xyz, out_xyz);
  transpose_kernel<<<dim3(64, Bc), 256, 0, stream>>>(points, pointsT);
  ball_kernel<<<(Bc*Sc)/4, 256, 0, stream>>>(xyz, out_xyz, ballidx);
  gather_kernel<<<Bc*Sc, 256, 0, stream>>>(xyz, out_xyz, pointsT, ballidx, X);

  // layer 0: ci=67 (pad 68), co=64
  mm_kernel<67,68,68><<<Mc/256, 256, 0, stream>>>(X, wc0, tp, Y, pS, pQ, 0);
  finalize_kernel<<<1, 256, 0, stream>>>(pS, pQ, g0, be0, scale, shift, Mc/256);
  norm_kernel<<<4096, 256, 0, stream>>>((const float4*)Y, scale, shift, (float4*)X, Mc*64/4);

  // layer 1: ci=64, co=64
  mm_kernel<64,64,64><<<Mc/256, 256, 0, stream>>>(X, wc1, tp + 544, Y, pS, pQ, 0);
  finalize_kernel<<<1, 256, 0, stream>>>(pS, pQ, g1, be1, scale, shift, Mc/256);
  norm_kernel<<<4096, 256, 0, stream>>>((const float4*)Y, scale, shift, (float4*)X, Mc*64/4);

  // layer 2: ci=64, co=128 in two 64-col halves, fused BN+GELU+maxpool
  mm_kernel<64,64,64><<<Mc/256, 256, 0, stream>>>(X, wc2, tp + 1088, Y, pS, pQ, 0);
  finalize_kernel<<<1, 256, 0, stream>>>(pS, pQ, g2, be2, scale, shift, Mc/256);
  pool_kernel<<<Bc*Sc/32, 256, 0, stream>>>(Y, scale, shift, out_pts, 0);

  mm_kernel<64,64,64><<<Mc/256, 256, 0, stream>>>(X, wc2, tp + 1088, Y, pS, pQ, 64);
  finalize_kernel<<<1, 256, 0, stream>>>(pS, pQ, g2+64, be2+64, scale, shift, Mc/256);
  pool_kernel<<<Bc*Sc/32, 256, 0, stream>>>(Y, scale, shift, out_pts, 64);
}